// Round 14
// baseline (161.519 us; speedup 1.0000x reference)
//
#include <hip/hip_runtime.h>

#define BATCHES 8
#define NPTS    100000
#define NPOINT  64
#define BPB     16                    // blocks per batch (champion config)
#define NTHREADS 512                  // 8 waves/block
#define WPB     (NTHREADS / 64)
#define TPB     (BPB * NTHREADS)      // threads per batch = 8192
#define KMAX    13                    // ceil(NPTS / TPB)
#define TAILN   (NPTS - (KMAX - 1) * TPB)

// workspace layout (zeroed per call by hipMemsetAsync)
#define WS_BARY_OFF 0                                    // [B][BPB][3] double = 3072 B
#define WS_CNT_OFF  3072                                 // [B] u32
#define WS_SLOT_OFF 4096                                 // [B][NPOINT][BPB] u64 = 65536 B
#define WS_CTRL_BYTES (WS_SLOT_OFF + BATCHES * NPOINT * BPB * 8)

// contraction-free f32 squared distance, numpy sum order (dx*dx + dy*dy) + dz*dz
__device__ __forceinline__ float sq3(float dx, float dy, float dz) {
    return __fadd_rn(__fadd_rn(__fmul_rn(dx, dx), __fmul_rn(dy, dy)), __fmul_rn(dz, dz));
}

__global__ __launch_bounds__(NTHREADS, 4)
void fps_kernel(const float* __restrict__ xyz, float* __restrict__ out,
                unsigned char* __restrict__ ws)
{
    double* baryPart = (double*)(ws + WS_BARY_OFF);
    unsigned int* cnt = (unsigned int*)(ws + WS_CNT_OFF);
    unsigned long long* slots = (unsigned long long*)(ws + WS_SLOT_OFF);

    const int b    = blockIdx.x & 7;          // XCD-pin heuristic (perf only)
    const int blk  = blockIdx.x >> 3;         // 0..15 within batch
    const int tid  = threadIdx.x;
    const int wid  = tid >> 6;
    const int lane = tid & 63;
    const int t    = blk * NTHREADS + tid;    // 0..TPB-1 within batch

    const float* xb = xyz + (size_t)b * NPTS * 3;

    __shared__ double bred[WPB][3];
    __shared__ unsigned long long kred[WPB];
    __shared__ float s_c[3];
    __shared__ int s_far;

    // bestd[] doubles as FPS dist[] (identical values at all times: winner's d==0 exactly
    // at its selection round, min-chain thereafter). Merged array, proven R12/R13.
    float px[KMAX], py[KMAX], pz[KMAX], bestd[KMAX];
    int besti[KMAX];
    const int nk = (t < TAILN) ? KMAX : (KMAX - 1);

    // ---- load points into registers; double partial sums for the mean ----
    double sx = 0.0, sy = 0.0, sz = 0.0;
    #pragma unroll
    for (int k = 0; k < KMAX; k++) {
        if (k < nk) {
            int p = t + k * TPB;
            float x = xb[p * 3 + 0], y = xb[p * 3 + 1], z = xb[p * 3 + 2];
            px[k] = x; py[k] = y; pz[k] = z;
            bestd[k] = 3.4e38f; besti[k] = 0;
            sx += (double)x; sy += (double)y; sz += (double)z;
        }
    }
    for (int off = 32; off > 0; off >>= 1) {
        sx += __shfl_down(sx, off); sy += __shfl_down(sy, off); sz += __shfl_down(sz, off);
    }
    if (lane == 0) { bred[wid][0] = sx; bred[wid][1] = sy; bred[wid][2] = sz; }
    __syncthreads();
    if (tid == 0) {
        double ax = 0, ay = 0, az = 0;
        for (int w = 0; w < WPB; w++) { ax += bred[w][0]; ay += bred[w][1]; az += bred[w][2]; }
        double* dst = baryPart + ((size_t)b * BPB + blk) * 3;
        dst[0] = ax; dst[1] = ay; dst[2] = az;
        __hip_atomic_fetch_add(&cnt[b], 1u, __ATOMIC_ACQ_REL, __HIP_MEMORY_SCOPE_AGENT);
        while (__hip_atomic_load(&cnt[b], __ATOMIC_ACQUIRE, __HIP_MEMORY_SCOPE_AGENT) < BPB)
            __builtin_amdgcn_s_sleep(2);
        double mx = 0, my = 0, mz = 0;
        for (int q = 0; q < BPB; q++) {       // deterministic fixed order
            const double* s2 = baryPart + ((size_t)b * BPB + q) * 3;
            mx += s2[0]; my += s2[1]; mz += s2[2];
        }
        s_c[0] = (float)(mx / (double)NPTS);
        s_c[1] = (float)(my / (double)NPTS);
        s_c[2] = (float)(mz / (double)NPTS);
    }
    __syncthreads();
    const float bx = s_c[0], by = s_c[1], bz = s_c[2];

    // ---- per-thread candidate 0: farthest from barycenter ----
    float bd = -1.0f; int bp = 0;
    #pragma unroll
    for (int k = 0; k < KMAX; k++) {
        if (k < nk) {
            int p = t + k * TPB;
            float d = sq3(__fsub_rn(px[k], bx), __fsub_rn(py[k], by), __fsub_rn(pz[k], bz));
            if (d > bd) { bd = d; bp = p; }
        }
    }
    unsigned long long key = (((unsigned long long)__float_as_uint(bd)) << 32)
                             | (unsigned)(0xFFFFFFFFu - (unsigned)bp);   // never 0

    // ================= 64 rounds (16 key-only slots in one line, wave0 polls) =================
    for (int e = 0; e < NPOINT; e++) {
        // wave reduce, lane0 posts to LDS
        unsigned long long wmax = key;
        for (int m = 32; m > 0; m >>= 1) {
            unsigned long long o = __shfl_xor(wmax, m); if (o > wmax) wmax = o;
        }
        if (lane == 0) kred[wid] = wmax;
        __syncthreads();

        if (wid == 0) {
            unsigned long long v = (lane < WPB) ? kred[lane] : 0ull;
            for (int m = 4; m > 0; m >>= 1) {
                unsigned long long o = __shfl_xor(v, m, 8); if (o > v) v = o;
            }
            unsigned long long* row = &slots[((size_t)b * NPOINT + e) * BPB];
            if (lane == 0)
                __hip_atomic_store(&row[blk], v, __ATOMIC_RELAXED, __HIP_MEMORY_SCOPE_AGENT);
            unsigned long long w = 0;
            if (lane < BPB) {
                while ((w = __hip_atomic_load(&row[lane], __ATOMIC_RELAXED,
                                              __HIP_MEMORY_SCOPE_AGENT)) == 0ull) { }
            }
            for (int m = 8; m > 0; m >>= 1) {
                unsigned long long o = __shfl_xor(w, m, 16); if (o > w) w = o;
            }
            if (lane == 0) {                   // R7-proven: lane0 fetch + LDS publish pre-barrier
                int f = (int)(0xFFFFFFFFu - (unsigned)(w & 0xFFFFFFFFull));
                s_far = f;
                s_c[0] = xb[f * 3 + 0]; s_c[1] = xb[f * 3 + 1]; s_c[2] = xb[f * 3 + 2];
            }
        }
        __syncthreads();                       // winner published

        const float cx = s_c[0], cy = s_c[1], cz = s_c[2];

        // output writes off the critical path (wave1, post-barrier, reads LDS)
        if (blk == 0 && wid == 1 && lane == 0) {
            out[((size_t)b * NPOINT + e) * 3 + 0] = cx;
            out[((size_t)b * NPOINT + e) * 3 + 1] = cy;
            out[((size_t)b * NPOINT + e) * 3 + 2] = cz;
            out[(size_t)BATCHES * NPOINT * 3 + b * NPOINT + e] = (float)s_far;
        }

        if (e == NPOINT - 1) {
            // final assignment fold vs centroid 63
            #pragma unroll
            for (int k = 0; k < KMAX; k++) {
                if (k < nk) {
                    float d = sq3(__fsub_rn(px[k], cx), __fsub_rn(py[k], cy), __fsub_rn(pz[k], cz));
                    if (d < bestd[k]) { bestd[k] = d; besti[k] = NPOINT - 1; }
                }
            }
            break;
        }

        // distance update == argmin fold (merged) + next candidate
        bd = -1.0f; bp = 0;
        #pragma unroll
        for (int k = 0; k < KMAX; k++) {
            if (k < nk) {
                float d = sq3(__fsub_rn(px[k], cx), __fsub_rn(py[k], cy), __fsub_rn(pz[k], cz));
                if (d < bestd[k]) { bestd[k] = d; besti[k] = e; }   // strict < => first-index
                float nd = bestd[k];                                // == min(dist, d)
                int p = t + k * TPB;
                if (nd > bd) { bd = nd; bp = p; }
            }
        }
        key = (((unsigned long long)__float_as_uint(bd)) << 32)
              | (unsigned)(0xFFFFFFFFu - (unsigned)bp);
    }

    float* outClust = out + (size_t)BATCHES * NPOINT * 3 + (size_t)BATCHES * NPOINT;
    #pragma unroll
    for (int k = 0; k < KMAX; k++)
        if (k < nk) outClust[(size_t)b * NPTS + t + k * TPB] = (float)besti[k];
}

extern "C" void kernel_launch(void* const* d_in, const int* in_sizes, int n_in,
                              void* d_out, int out_size, void* d_ws, size_t ws_size,
                              hipStream_t stream) {
    const float* xyz = (const float*)d_in[0];
    float* out = (float*)d_out;
    hipMemsetAsync(d_ws, 0, WS_CTRL_BYTES, stream);
    fps_kernel<<<dim3(BATCHES * BPB), dim3(NTHREADS), 0, stream>>>(
        xyz, out, (unsigned char*)d_ws);
}

// Round 15
// 149.304 us; speedup vs baseline: 1.0818x; 1.0818x over previous
//
#include <hip/hip_runtime.h>

#define BATCHES 8
#define NPTS    100000
#define NPOINT  64
#define BPB     16                    // blocks per batch
#define NTHREADS 512                  // 8 waves/block (2 per SIMD)
#define WPB     (NTHREADS / 64)
#define TPB     (BPB * NTHREADS)      // threads per batch = 8192
#define KMAX    13                    // ceil(NPTS / TPB)
#define TAILN   (NPTS - (KMAX - 1) * TPB)

// workspace layout (zeroed per call by hipMemsetAsync)
#define WS_BARY_OFF 0                                    // [B][BPB][3] double = 3072 B
#define WS_CNT_OFF  3072                                 // [B] u32
#define WS_SLOT_OFF 4096                                 // [B][NPOINT][BPB] u64 = 65536 B
#define WS_CTRL_BYTES (WS_SLOT_OFF + BATCHES * NPOINT * BPB * 8)

// contraction-free f32 squared distance, numpy sum order (dx*dx + dy*dy) + dz*dz
__device__ __forceinline__ float sq3(float dx, float dy, float dz) {
    return __fadd_rn(__fadd_rn(__fmul_rn(dx, dx), __fmul_rn(dy, dy)), __fmul_rn(dz, dz));
}

__global__ __launch_bounds__(NTHREADS, 4)
void fps_kernel(const float* __restrict__ xyz, float* __restrict__ out,
                unsigned char* __restrict__ ws)
{
    double* baryPart = (double*)(ws + WS_BARY_OFF);
    unsigned int* cnt = (unsigned int*)(ws + WS_CNT_OFF);
    unsigned long long* slots = (unsigned long long*)(ws + WS_SLOT_OFF);

    const int b    = blockIdx.x & 7;          // XCD-pin: same-batch blocks -> same XCD (heuristic)
    const int blk  = blockIdx.x >> 3;         // 0..15 within batch
    const int tid  = threadIdx.x;
    const int wid  = tid >> 6;
    const int lane = tid & 63;
    const int t    = blk * NTHREADS + tid;    // 0..TPB-1 within batch

    const float* xb = xyz + (size_t)b * NPTS * 3;

    __shared__ double bred[WPB][3];
    __shared__ unsigned long long kred[WPB];
    __shared__ float s_c[3];
    __shared__ int s_far;

    float px[KMAX], py[KMAX], pz[KMAX], dist[KMAX];
    float bestd[KMAX]; int besti[KMAX];
    const int nk = (t < TAILN) ? KMAX : (KMAX - 1);

    // ---- load points into registers; double partial sums for the mean ----
    double sx = 0.0, sy = 0.0, sz = 0.0;
    #pragma unroll
    for (int k = 0; k < KMAX; k++) {
        if (k < nk) {
            int p = t + k * TPB;
            float x = xb[p * 3 + 0], y = xb[p * 3 + 1], z = xb[p * 3 + 2];
            px[k] = x; py[k] = y; pz[k] = z; dist[k] = 1e10f;
            bestd[k] = 3.4e38f; besti[k] = 0;
            sx += (double)x; sy += (double)y; sz += (double)z;
        }
    }
    for (int off = 32; off > 0; off >>= 1) {
        sx += __shfl_down(sx, off); sy += __shfl_down(sy, off); sz += __shfl_down(sz, off);
    }
    if (lane == 0) { bred[wid][0] = sx; bred[wid][1] = sy; bred[wid][2] = sz; }
    __syncthreads();
    if (tid == 0) {
        double ax = 0, ay = 0, az = 0;
        for (int w = 0; w < WPB; w++) { ax += bred[w][0]; ay += bred[w][1]; az += bred[w][2]; }
        double* dst = baryPart + ((size_t)b * BPB + blk) * 3;
        dst[0] = ax; dst[1] = ay; dst[2] = az;
        __hip_atomic_fetch_add(&cnt[b], 1u, __ATOMIC_ACQ_REL, __HIP_MEMORY_SCOPE_AGENT);
        while (__hip_atomic_load(&cnt[b], __ATOMIC_ACQUIRE, __HIP_MEMORY_SCOPE_AGENT) < BPB)
            __builtin_amdgcn_s_sleep(2);
        double mx = 0, my = 0, mz = 0;
        for (int q = 0; q < BPB; q++) {       // deterministic fixed order
            const double* s2 = baryPart + ((size_t)b * BPB + q) * 3;
            mx += s2[0]; my += s2[1]; mz += s2[2];
        }
        s_c[0] = (float)(mx / (double)NPTS);
        s_c[1] = (float)(my / (double)NPTS);
        s_c[2] = (float)(mz / (double)NPTS);
    }
    __syncthreads();
    const float bx = s_c[0], by = s_c[1], bz = s_c[2];

    // ---- per-thread candidate 0: farthest from barycenter ----
    float bd = -1.0f; int bp = 0;
    #pragma unroll
    for (int k = 0; k < KMAX; k++) {
        if (k < nk) {
            int p = t + k * TPB;
            float d = sq3(__fsub_rn(px[k], bx), __fsub_rn(py[k], by), __fsub_rn(pz[k], bz));
            if (d > bd) { bd = d; bp = p; }
        }
    }
    unsigned long long key = (((unsigned long long)__float_as_uint(bd)) << 32)
                             | (unsigned)(0xFFFFFFFFu - (unsigned)bp);

    // ================= 64 rounds (16 key-only slots, wave0 polls) =================
    for (int e = 0; e < NPOINT; e++) {
        // wave reduce, lane0 posts to LDS
        unsigned long long wmax = key;
        for (int m = 32; m > 0; m >>= 1) {
            unsigned long long o = __shfl_xor(wmax, m); if (o > wmax) wmax = o;
        }
        if (lane == 0) kred[wid] = wmax;
        __syncthreads();

        if (wid == 0) {
            unsigned long long v = (lane < WPB) ? kred[lane] : 0ull;
            for (int m = 4; m > 0; m >>= 1) {
                unsigned long long o = __shfl_xor(v, m, 8); if (o > v) v = o;
            }
            unsigned long long* row = &slots[((size_t)b * NPOINT + e) * BPB];
            if (lane == 0)
                __hip_atomic_store(&row[blk], v, __ATOMIC_RELAXED, __HIP_MEMORY_SCOPE_AGENT);
            unsigned long long w = 0;
            if (lane < BPB) {
                while ((w = __hip_atomic_load(&row[lane], __ATOMIC_RELAXED,
                                              __HIP_MEMORY_SCOPE_AGENT)) == 0ull) { }
            }
            for (int m = 8; m > 0; m >>= 1) {
                unsigned long long o = __shfl_xor(w, m, 16); if (o > w) w = o;
            }
            if (lane == 0) {
                int f = (int)(0xFFFFFFFFu - (unsigned)(w & 0xFFFFFFFFull));
                float cx = xb[f * 3 + 0], cy = xb[f * 3 + 1], cz = xb[f * 3 + 2];
                s_far = f; s_c[0] = cx; s_c[1] = cy; s_c[2] = cz;
                if (blk == 0) {
                    out[((size_t)b * NPOINT + e) * 3 + 0] = cx;
                    out[((size_t)b * NPOINT + e) * 3 + 1] = cy;
                    out[((size_t)b * NPOINT + e) * 3 + 2] = cz;
                    out[(size_t)BATCHES * NPOINT * 3 + b * NPOINT + e] = (float)f;
                }
            }
        }
        __syncthreads();                       // winner published
        if (e == NPOINT - 1) break;

        // distance update + assignment fold + next candidate
        const float cx = s_c[0], cy = s_c[1], cz = s_c[2];
        bd = -1.0f; bp = 0;
        #pragma unroll
        for (int k = 0; k < KMAX; k++) {
            if (k < nk) {
                float d = sq3(__fsub_rn(px[k], cx), __fsub_rn(py[k], cy), __fsub_rn(pz[k], cz));
                if (d < bestd[k]) { bestd[k] = d; besti[k] = e; }   // argmin fold (first-index)
                float nd = fminf(dist[k], d);                       // winner's d==0 exactly
                dist[k] = nd;
                int p = t + k * TPB;
                if (nd > bd) { bd = nd; bp = p; }
            }
        }
        key = (((unsigned long long)__float_as_uint(bd)) << 32)
              | (unsigned)(0xFFFFFFFFu - (unsigned)bp);
    }

    // ---- final assignment pass vs centroid 63 (loop broke before updating) ----
    {
        const float cx = s_c[0], cy = s_c[1], cz = s_c[2];
        #pragma unroll
        for (int k = 0; k < KMAX; k++) {
            if (k < nk) {
                float d = sq3(__fsub_rn(px[k], cx), __fsub_rn(py[k], cy), __fsub_rn(pz[k], cz));
                if (d < bestd[k]) { bestd[k] = d; besti[k] = NPOINT - 1; }
            }
        }
    }

    float* outClust = out + (size_t)BATCHES * NPOINT * 3 + (size_t)BATCHES * NPOINT;
    #pragma unroll
    for (int k = 0; k < KMAX; k++)
        if (k < nk) outClust[(size_t)b * NPTS + t + k * TPB] = (float)besti[k];
}

extern "C" void kernel_launch(void* const* d_in, const int* in_sizes, int n_in,
                              void* d_out, int out_size, void* d_ws, size_t ws_size,
                              hipStream_t stream) {
    const float* xyz = (const float*)d_in[0];
    float* out = (float*)d_out;
    hipMemsetAsync(d_ws, 0, WS_CTRL_BYTES, stream);
    fps_kernel<<<dim3(BATCHES * BPB), dim3(NTHREADS), 0, stream>>>(
        xyz, out, (unsigned char*)d_ws);
}